// Round 1
// baseline (5078.095 us; speedup 1.0000x reference)
//
#include <hip/hip_runtime.h>
#include <math.h>

#define N_NODES 200000
#define MEM_DIM 128
#define E_EDGES 100000
#define TIME_DIM 100
#define RAW_DIM 484   // 128 + 128 + 128 + 100

// ---------------------------------------------------------------------------
// Kernel A: per-edge message MLP + scatter-add into sums/counts (held in d_out)
//   sums   = d_out[0 .. N*128)
//   counts = d_out[N*128 .. N*128 + N)
// ---------------------------------------------------------------------------
#define TE 32  // edges per block

__global__ __launch_bounds__(256) void tgn_msg_kernel(
    const float* __restrict__ memory,
    const float* __restrict__ last_update,
    const float* __restrict__ timestamps,
    const float* __restrict__ edge_features,
    const float* __restrict__ msg_W,    // [128][484]
    const float* __restrict__ msg_b,    // [128]
    const float* __restrict__ time_w,   // [100]
    const float* __restrict__ time_b,   // [100]
    const int*   __restrict__ src,
    const int*   __restrict__ dst,
    float* __restrict__ sums,
    float* __restrict__ counts)
{
    __shared__ float raw[TE][RAW_DIM];   // 32*484*4 = 61952 B
    __shared__ int   sid[TE];
    __shared__ int   did[TE];

    const int tid = threadIdx.x;
    const int e0  = blockIdx.x * TE;

    if (tid < TE) {
        int s = src[e0 + tid];
        int d = dst[e0 + tid];
        sid[tid] = s;
        did[tid] = d;
        atomicAdd(&counts[s], 1.0f);
        atomicAdd(&counts[d], 1.0f);
    }
    __syncthreads();

    // Stage raw = [src_mem | dst_mem | edge_feat | time_feat] for 32 edges.
    for (int idx = tid; idx < TE * 512; idx += 256) {
        int e = idx >> 9;
        int k = idx & 511;
        if (k < RAW_DIM) {
            float v;
            if (k < 128) {
                v = memory[sid[e] * 128 + k];
            } else if (k < 256) {
                v = memory[did[e] * 128 + (k - 128)];
            } else if (k < 384) {
                v = edge_features[(e0 + e) * 128 + (k - 256)];
            } else {
                int t = k - 384;
                float dt = timestamps[e0 + e] - last_update[sid[e]];
                v = cosf(dt * time_w[t] + time_b[t]);
            }
            raw[e][k] = v;
        }
    }
    __syncthreads();

    // Register-tiled GEMM: 256 threads = 32 output-groups x 8 edge-groups,
    // each thread computes 4 edges x 4 outputs.
    const int og = tid & 31;   // output group: outputs og*4 .. og*4+3
    const int eg = tid >> 5;   // edge group:   edges   eg*4 .. eg*4+3

    float acc[4][4];
#pragma unroll
    for (int a = 0; a < 4; a++)
#pragma unroll
        for (int b = 0; b < 4; b++) acc[a][b] = 0.0f;

    for (int k = 0; k < RAW_DIM; k += 4) {
        float4 w4[4];
#pragma unroll
        for (int o = 0; o < 4; o++) {
            w4[o] = *reinterpret_cast<const float4*>(msg_W + (og * 4 + o) * RAW_DIM + k);
        }
        float4 r4[4];
#pragma unroll
        for (int e = 0; e < 4; e++) {
            r4[e] = *reinterpret_cast<const float4*>(&raw[eg * 4 + e][k]);
        }
#pragma unroll
        for (int e = 0; e < 4; e++) {
#pragma unroll
            for (int o = 0; o < 4; o++) {
                acc[e][o] += r4[e].x * w4[o].x + r4[e].y * w4[o].y +
                             r4[e].z * w4[o].z + r4[e].w * w4[o].w;
            }
        }
    }

    // Epilogue: add bias, atomic scatter-add to both endpoints.
#pragma unroll
    for (int e = 0; e < 4; e++) {
        int ei = eg * 4 + e;
        int s = sid[ei];
        int d = did[ei];
#pragma unroll
        for (int o = 0; o < 4; o++) {
            int oi = og * 4 + o;
            float m = acc[e][o] + msg_b[oi];
            atomicAdd(&sums[s * 128 + oi], m);
            atomicAdd(&sums[d * 128 + oi], m);
        }
    }
}

// ---------------------------------------------------------------------------
// Kernel B: GRU update per node tile (in-place over the sums/counts in d_out)
// ---------------------------------------------------------------------------
#define TN 16  // nodes per block

__global__ __launch_bounds__(256) void tgn_gru_kernel(
    const float* __restrict__ memory,
    const float* __restrict__ last_update,
    const float* __restrict__ timestamps,
    const float* __restrict__ W_ih,   // [384][128]
    const float* __restrict__ W_hh,   // [384][128]
    const float* __restrict__ b_ih,   // [384]
    const float* __restrict__ b_hh,   // [384]
    float* __restrict__ out)          // full d_out
{
    __shared__ float aggS[TN][128];
    __shared__ float memS[TN][128];
    __shared__ float cntS[TN];

    const int tid = threadIdx.x;
    const int n0  = blockIdx.x * TN;

    float* sums   = out;
    float* counts = out + (size_t)N_NODES * 128;

    if (tid < TN) cntS[tid] = counts[n0 + tid];
    __syncthreads();

    for (int idx = tid; idx < TN * 128; idx += 256) {
        int n = idx >> 7;
        int j = idx & 127;
        float c = fmaxf(cntS[n], 1.0f);
        aggS[n][j] = sums[(n0 + n) * 128 + j] / c;
        memS[n][j] = memory[(n0 + n) * 128 + j];
    }
    __syncthreads();

    // 256 threads = 32 j-groups x 8 node-groups; each thread: 2 nodes x 4 dims
    // x 3 gates x 2 matrices.
    const int og = tid & 31;   // dims j = og*4 .. og*4+3
    const int ng = tid >> 5;   // nodes ng*2, ng*2+1

    float accI[2][3][4];
    float accH[2][3][4];
#pragma unroll
    for (int n = 0; n < 2; n++)
#pragma unroll
        for (int g = 0; g < 3; g++)
#pragma unroll
            for (int o = 0; o < 4; o++) { accI[n][g][o] = 0.0f; accH[n][g][o] = 0.0f; }

#pragma unroll 2
    for (int k = 0; k < 128; k += 4) {
        float4 a4[2], m4[2];
#pragma unroll
        for (int n = 0; n < 2; n++) {
            a4[n] = *reinterpret_cast<const float4*>(&aggS[ng * 2 + n][k]);
            m4[n] = *reinterpret_cast<const float4*>(&memS[ng * 2 + n][k]);
        }
#pragma unroll
        for (int g = 0; g < 3; g++) {
#pragma unroll
            for (int o = 0; o < 4; o++) {
                int row = g * 128 + og * 4 + o;
                float4 wi = *reinterpret_cast<const float4*>(W_ih + row * 128 + k);
                float4 wh = *reinterpret_cast<const float4*>(W_hh + row * 128 + k);
#pragma unroll
                for (int n = 0; n < 2; n++) {
                    accI[n][g][o] += a4[n].x * wi.x + a4[n].y * wi.y +
                                     a4[n].z * wi.z + a4[n].w * wi.w;
                    accH[n][g][o] += m4[n].x * wh.x + m4[n].y * wh.y +
                                     m4[n].z * wh.z + m4[n].w * wh.w;
                }
            }
        }
    }

    const float ts0 = timestamps[0];

#pragma unroll
    for (int n = 0; n < 2; n++) {
        int ni   = ng * 2 + n;
        int node = n0 + ni;
        bool active = cntS[ni] > 0.0f;
#pragma unroll
        for (int o = 0; o < 4; o++) {
            int j = og * 4 + o;
            float ir = accI[n][0][o] + b_ih[j];
            float iz = accI[n][1][o] + b_ih[128 + j];
            float in_ = accI[n][2][o] + b_ih[256 + j];
            float hr = accH[n][0][o] + b_hh[j];
            float hz = accH[n][1][o] + b_hh[128 + j];
            float hn = accH[n][2][o] + b_hh[256 + j];
            float r = 1.0f / (1.0f + expf(-(ir + hr)));
            float z = 1.0f / (1.0f + expf(-(iz + hz)));
            float nn = tanhf(in_ + r * hn);
            float mv = memS[ni][j];
            float h  = (1.0f - z) * nn + z * mv;
            out[(size_t)node * 128 + j] = active ? h : mv;
        }
    }

    if (tid < TN) {
        int node = n0 + tid;
        bool active = cntS[tid] > 0.0f;
        out[(size_t)N_NODES * 128 + node] = active ? ts0 : last_update[node];
    }
}

// ---------------------------------------------------------------------------
extern "C" void kernel_launch(void* const* d_in, const int* in_sizes, int n_in,
                              void* d_out, int out_size, void* d_ws, size_t ws_size,
                              hipStream_t stream) {
    const float* memory        = (const float*)d_in[0];
    const float* last_update   = (const float*)d_in[1];
    const float* timestamps    = (const float*)d_in[2];
    const float* edge_features = (const float*)d_in[3];
    const float* msg_W         = (const float*)d_in[4];
    const float* msg_b         = (const float*)d_in[5];
    const float* gru_W_ih      = (const float*)d_in[6];
    const float* gru_W_hh      = (const float*)d_in[7];
    const float* gru_b_ih      = (const float*)d_in[8];
    const float* gru_b_hh      = (const float*)d_in[9];
    const float* time_w        = (const float*)d_in[10];
    const float* time_b        = (const float*)d_in[11];
    const int*   src           = (const int*)d_in[12];
    const int*   dst           = (const int*)d_in[13];

    float* out = (float*)d_out;

    // Zero the sums/counts accumulators (they live in d_out itself).
    hipMemsetAsync(d_out, 0, (size_t)out_size * sizeof(float), stream);

    float* sums   = out;
    float* counts = out + (size_t)N_NODES * 128;

    tgn_msg_kernel<<<E_EDGES / TE, 256, 0, stream>>>(
        memory, last_update, timestamps, edge_features, msg_W, msg_b,
        time_w, time_b, src, dst, sums, counts);

    tgn_gru_kernel<<<N_NODES / TN, 256, 0, stream>>>(
        memory, last_update, timestamps, gru_W_ih, gru_W_hh, gru_b_ih, gru_b_hh,
        out);
}

// Round 2
// 1160.091 us; speedup vs baseline: 4.3773x; 4.3773x over previous
//
#include <hip/hip_runtime.h>
#include <math.h>

#define N_NODES 200000
#define E_EDGES 100000
#define TIME_DIM 100
#define RAW_DIM 484   // 128 + 128 + 128 + 100

typedef short  bf16x8 __attribute__((ext_vector_type(8)));
typedef float  f32x4  __attribute__((ext_vector_type(4)));

__device__ __forceinline__ short f2bf(float f) {
    unsigned u = __builtin_bit_cast(unsigned, f);
    u = (u + 0x7FFFu + ((u >> 16) & 1u)) >> 16;   // RNE
    return (short)u;
}

// ---------------------------------------------------------------------------
// Kernel A: per-edge message MLP + scatter-add into sums/counts (held in d_out)
// ---------------------------------------------------------------------------
#define TE 32  // edges per block

__global__ __launch_bounds__(256) void tgn_msg_kernel(
    const float* __restrict__ memory,
    const float* __restrict__ last_update,
    const float* __restrict__ timestamps,
    const float* __restrict__ edge_features,
    const float* __restrict__ msg_W,    // [128][484]
    const float* __restrict__ msg_b,    // [128]
    const float* __restrict__ time_w,   // [100]
    const float* __restrict__ time_b,   // [100]
    const int*   __restrict__ src,
    const int*   __restrict__ dst,
    float* __restrict__ sums,
    float* __restrict__ counts)
{
    __shared__ float raw[TE][RAW_DIM];   // 32*484*4 = 61952 B
    __shared__ int   sid[TE];
    __shared__ int   did[TE];

    const int tid = threadIdx.x;
    const int e0  = blockIdx.x * TE;

    if (tid < TE) {
        int s = src[e0 + tid];
        int d = dst[e0 + tid];
        sid[tid] = s;
        did[tid] = d;
        atomicAdd(&counts[s], 1.0f);
        atomicAdd(&counts[d], 1.0f);
    }
    __syncthreads();

    for (int idx = tid; idx < TE * 512; idx += 256) {
        int e = idx >> 9;
        int k = idx & 511;
        if (k < RAW_DIM) {
            float v;
            if (k < 128) {
                v = memory[(size_t)sid[e] * 128 + k];
            } else if (k < 256) {
                v = memory[(size_t)did[e] * 128 + (k - 128)];
            } else if (k < 384) {
                v = edge_features[(size_t)(e0 + e) * 128 + (k - 256)];
            } else {
                int t = k - 384;
                float dt = timestamps[e0 + e] - last_update[sid[e]];
                v = cosf(dt * time_w[t] + time_b[t]);
            }
            raw[e][k] = v;
        }
    }
    __syncthreads();

    const int og = tid & 31;   // outputs og*4 .. og*4+3
    const int eg = tid >> 5;   // edges   eg*4 .. eg*4+3

    float acc[4][4];
#pragma unroll
    for (int a = 0; a < 4; a++)
#pragma unroll
        for (int b = 0; b < 4; b++) acc[a][b] = 0.0f;

    for (int k = 0; k < RAW_DIM; k += 4) {
        float4 w4[4];
#pragma unroll
        for (int o = 0; o < 4; o++)
            w4[o] = *reinterpret_cast<const float4*>(msg_W + (size_t)(og * 4 + o) * RAW_DIM + k);
        float4 r4[4];
#pragma unroll
        for (int e = 0; e < 4; e++)
            r4[e] = *reinterpret_cast<const float4*>(&raw[eg * 4 + e][k]);
#pragma unroll
        for (int e = 0; e < 4; e++)
#pragma unroll
            for (int o = 0; o < 4; o++)
                acc[e][o] += r4[e].x * w4[o].x + r4[e].y * w4[o].y +
                             r4[e].z * w4[o].z + r4[e].w * w4[o].w;
    }

#pragma unroll
    for (int e = 0; e < 4; e++) {
        int ei = eg * 4 + e;
        int s = sid[ei];
        int d = did[ei];
#pragma unroll
        for (int o = 0; o < 4; o++) {
            int oi = og * 4 + o;
            float m = acc[e][o] + msg_b[oi];
            atomicAdd(&sums[(size_t)s * 128 + oi], m);
            atomicAdd(&sums[(size_t)d * 128 + oi], m);
        }
    }
}

// ---------------------------------------------------------------------------
// Prep: pack combined GRU weight matrix W_big[512][256] into MFMA B-fragment
// order (bf16).  W_big row n (output), col k:
//   n in [0,128):   r   -> [W_ih[n]       | W_hh[n]      ]
//   n in [128,256): z   -> [W_ih[n]       | W_hh[n]      ]
//   n in [256,384): i_n -> [W_ih[n]       | 0            ]
//   n in [384,512): h_n -> [0             | W_hh[n-128]  ]
// Fragment order: wf[t][s][l][j]  (t = n-tile 0..31, s = k-step 0..7,
//   l = lane, j = 0..7), element = W_big[t*16 + (l&15)][s*32 + (l>>4)*8 + j]
// ---------------------------------------------------------------------------
__global__ __launch_bounds__(256) void tgn_prep_wfrag(
    const float* __restrict__ Wih,   // [384][128]
    const float* __restrict__ Whh,   // [384][128]
    short* __restrict__ wf)
{
    int idx = blockIdx.x * 256 + threadIdx.x;   // 0 .. 131071
    int j = idx & 7;
    int l = (idx >> 3) & 63;
    int s = (idx >> 9) & 7;
    int t = idx >> 12;
    int n = t * 16 + (l & 15);
    int k = s * 32 + (l >> 4) * 8 + j;
    int half = k >> 7;      // 0: agg/ih half, 1: mem/hh half
    int kk = k & 127;
    float v;
    if (n < 256) {
        v = half ? Whh[(size_t)n * 128 + kk] : Wih[(size_t)n * 128 + kk];
    } else if (n < 384) {
        v = half ? 0.0f : Wih[(size_t)n * 128 + kk];          // i_n rows 256..383
    } else {
        v = half ? Whh[(size_t)(n - 128) * 128 + kk] : 0.0f;  // h_n rows 256..383 of Whh
    }
    wf[idx] = f2bf(v);
}

// ---------------------------------------------------------------------------
// Kernel B: fused MFMA GEMM + GRU gates.  64 nodes/block, 256 threads.
// Wave w owns j-slice [w*32, w*32+32) and all 4 gate quadrants for it.
// ---------------------------------------------------------------------------
#define NT 64

__global__ __launch_bounds__(256, 2) void tgn_gru_mfma(
    const float* __restrict__ memory,
    const float* __restrict__ last_update,
    const float* __restrict__ timestamps,
    const float* __restrict__ b_ih,
    const float* __restrict__ b_hh,
    const short* __restrict__ wfrag,
    float* __restrict__ out)
{
    __shared__ short X[NT][264];     // [node][k=256 + pad 8], stride 528 B
    __shared__ float cntS[NT];

    const int tid = threadIdx.x;
    const int n0 = blockIdx.x * NT;
    const float* sums   = out;
    const float* counts = out + (size_t)N_NODES * 128;

    if (tid < NT) cntS[tid] = counts[n0 + tid];
    __syncthreads();

    // Stage X = [agg | mem] as bf16
    for (int i = tid; i < NT * 64; i += 256) {
        int m = i >> 6;
        int c = (i & 63) * 4;
        float4 v;
        if (c < 128) {
            v = *reinterpret_cast<const float4*>(&sums[(size_t)(n0 + m) * 128 + c]);
            float inv = 1.0f / fmaxf(cntS[m], 1.0f);
            v.x *= inv; v.y *= inv; v.z *= inv; v.w *= inv;
        } else {
            v = *reinterpret_cast<const float4*>(&memory[(size_t)(n0 + m) * 128 + (c - 128)]);
        }
        X[m][c + 0] = f2bf(v.x);
        X[m][c + 1] = f2bf(v.y);
        X[m][c + 2] = f2bf(v.z);
        X[m][c + 3] = f2bf(v.w);
    }
    __syncthreads();

    const int w    = tid >> 6;
    const int l    = tid & 63;
    const int lrow = l & 15;
    const int lkg  = l >> 4;

    f32x4 acc[4][2][4];   // [quadrant][jt][mt]
#pragma unroll
    for (int q = 0; q < 4; q++)
#pragma unroll
        for (int jt = 0; jt < 2; jt++)
#pragma unroll
            for (int mt = 0; mt < 4; mt++)
                acc[q][jt][mt] = (f32x4){0.f, 0.f, 0.f, 0.f};

    for (int s = 0; s < 8; ++s) {
        bf16x8 A[4];
#pragma unroll
        for (int mt = 0; mt < 4; ++mt)
            A[mt] = *reinterpret_cast<const bf16x8*>(&X[mt * 16 + lrow][s * 32 + lkg * 8]);
        bf16x8 B[4][2];
#pragma unroll
        for (int q = 0; q < 4; ++q)
#pragma unroll
            for (int jt = 0; jt < 2; ++jt) {
                int t = q * 8 + w * 2 + jt;
                B[q][jt] = *reinterpret_cast<const bf16x8*>(&wfrag[(size_t)(((t * 8 + s) * 64) + l) * 8]);
            }
#pragma unroll
        for (int q = 0; q < 4; ++q)
#pragma unroll
            for (int jt = 0; jt < 2; ++jt)
#pragma unroll
                for (int mt = 0; mt < 4; ++mt)
                    acc[q][jt][mt] = __builtin_amdgcn_mfma_f32_16x16x32_bf16(
                        A[mt], B[q][jt], acc[q][jt][mt], 0, 0, 0);
    }

    const float ts0 = timestamps[0];

#pragma unroll
    for (int jt = 0; jt < 2; ++jt) {
        int j = w * 32 + jt * 16 + lrow;
        float br  = b_ih[j]       + b_hh[j];
        float bz  = b_ih[128 + j] + b_hh[128 + j];
        float bin = b_ih[256 + j];
        float bhn = b_hh[256 + j];
#pragma unroll
        for (int mt = 0; mt < 4; ++mt) {
#pragma unroll
            for (int r = 0; r < 4; ++r) {
                int mloc = mt * 16 + lkg * 4 + r;
                int node = n0 + mloc;
                float rg  = acc[0][jt][mt][r] + br;
                float zg  = acc[1][jt][mt][r] + bz;
                float ing = acc[2][jt][mt][r] + bin;
                float hng = acc[3][jt][mt][r] + bhn;
                float rr = 1.0f / (1.0f + __expf(-rg));
                float zz = 1.0f / (1.0f + __expf(-zg));
                float nn = tanhf(ing + rr * hng);
                float mv = memory[(size_t)node * 128 + j];
                float h  = (1.0f - zz) * nn + zz * mv;
                out[(size_t)node * 128 + j] = (cntS[mloc] > 0.0f) ? h : mv;
            }
        }
    }

    if (tid < NT) {
        int node = n0 + tid;
        out[(size_t)N_NODES * 128 + node] = (cntS[tid] > 0.0f) ? ts0 : last_update[node];
    }
}

// ---------------------------------------------------------------------------
extern "C" void kernel_launch(void* const* d_in, const int* in_sizes, int n_in,
                              void* d_out, int out_size, void* d_ws, size_t ws_size,
                              hipStream_t stream) {
    const float* memory        = (const float*)d_in[0];
    const float* last_update   = (const float*)d_in[1];
    const float* timestamps    = (const float*)d_in[2];
    const float* edge_features = (const float*)d_in[3];
    const float* msg_W         = (const float*)d_in[4];
    const float* msg_b         = (const float*)d_in[5];
    const float* gru_W_ih      = (const float*)d_in[6];
    const float* gru_W_hh      = (const float*)d_in[7];
    const float* gru_b_ih      = (const float*)d_in[8];
    const float* gru_b_hh      = (const float*)d_in[9];
    const float* time_w        = (const float*)d_in[10];
    const float* time_b        = (const float*)d_in[11];
    const int*   src           = (const int*)d_in[12];
    const int*   dst           = (const int*)d_in[13];

    float* out = (float*)d_out;
    short* wfrag = (short*)d_ws;   // 131072 bf16 = 256 KB

    hipMemsetAsync(d_out, 0, (size_t)out_size * sizeof(float), stream);

    float* sums   = out;
    float* counts = out + (size_t)N_NODES * 128;

    tgn_prep_wfrag<<<512, 256, 0, stream>>>(gru_W_ih, gru_W_hh, wfrag);

    tgn_msg_kernel<<<E_EDGES / TE, 256, 0, stream>>>(
        memory, last_update, timestamps, edge_features, msg_W, msg_b,
        time_w, time_b, src, dst, sums, counts);

    tgn_gru_mfma<<<N_NODES / NT, 256, 0, stream>>>(
        memory, last_update, timestamps, gru_b_ih, gru_b_hh, wfrag, out);
}

// Round 3
// 413.074 us; speedup vs baseline: 12.2934x; 2.8084x over previous
//
#include <hip/hip_runtime.h>
#include <math.h>

#define N_NODES 200000
#define E_EDGES 100000
#define TIME_DIM 100
#define RAW_DIM 484   // 128 + 128 + 128 + 100

typedef short  bf16x8 __attribute__((ext_vector_type(8)));
typedef float  f32x4  __attribute__((ext_vector_type(4)));

__device__ __forceinline__ short f2bf(float f) {
    unsigned u = __builtin_bit_cast(unsigned, f);
    u = (u + 0x7FFFu + ((u >> 16) & 1u)) >> 16;   // RNE
    return (short)u;
}

// ---------------------------------------------------------------------------
// Prep 1: pack msg_W [128][484] -> bf16 B-fragment order, K padded to 512.
// wfm[t][s][l][j], t=0..7 (n-tile), s=0..15 (k-step), l=lane, j=0..7
//   element = msg_W[t*16 + (l&15)][s*32 + (l>>4)*8 + j]  (0 for k>=484)
// ---------------------------------------------------------------------------
__global__ __launch_bounds__(256) void tgn_prep_wmsg(
    const float* __restrict__ msgW,   // [128][484]
    short* __restrict__ wf)
{
    int idx = blockIdx.x * 256 + threadIdx.x;   // 0 .. 65535
    int j = idx & 7;
    int l = (idx >> 3) & 63;
    int s = (idx >> 9) & 15;
    int t = idx >> 13;
    int n = t * 16 + (l & 15);
    int k = s * 32 + (l >> 4) * 8 + j;
    float v = (k < RAW_DIM) ? msgW[(size_t)n * RAW_DIM + k] : 0.0f;
    wf[idx] = f2bf(v);
}

// ---------------------------------------------------------------------------
// Prep 2: pack combined GRU weight matrix W_big[512][256] into B-frag order.
//   n in [0,128):   r   -> [W_ih[n] | W_hh[n]]
//   n in [128,256): z   -> [W_ih[n] | W_hh[n]]
//   n in [256,384): i_n -> [W_ih[n] | 0      ]
//   n in [384,512): h_n -> [0       | W_hh[n-128]]
// ---------------------------------------------------------------------------
__global__ __launch_bounds__(256) void tgn_prep_wgru(
    const float* __restrict__ Wih,   // [384][128]
    const float* __restrict__ Whh,   // [384][128]
    short* __restrict__ wf)
{
    int idx = blockIdx.x * 256 + threadIdx.x;   // 0 .. 131071
    int j = idx & 7;
    int l = (idx >> 3) & 63;
    int s = (idx >> 9) & 7;
    int t = idx >> 12;
    int n = t * 16 + (l & 15);
    int k = s * 32 + (l >> 4) * 8 + j;
    int half = k >> 7;
    int kk = k & 127;
    float v;
    if (n < 256) {
        v = half ? Whh[(size_t)n * 128 + kk] : Wih[(size_t)n * 128 + kk];
    } else if (n < 384) {
        v = half ? 0.0f : Wih[(size_t)n * 128 + kk];
    } else {
        v = half ? Whh[(size_t)(n - 128) * 128 + kk] : 0.0f;
    }
    wf[idx] = f2bf(v);
}

// ---------------------------------------------------------------------------
// Kernel A: MFMA message MLP + atomic scatter-add into sums/counts.
// 32 edges/block, 256 threads = 4 waves.
// wave w: edge-tile et=w&1 (16 edges), output-half nh=w>>1 (64 outputs).
// ---------------------------------------------------------------------------
#define TE 32

__global__ __launch_bounds__(256, 2) void tgn_msg_mfma(
    const float* __restrict__ memory,
    const float* __restrict__ last_update,
    const float* __restrict__ timestamps,
    const float* __restrict__ edge_features,
    const float* __restrict__ msg_b,
    const float* __restrict__ time_w,
    const float* __restrict__ time_b,
    const int*   __restrict__ src,
    const int*   __restrict__ dst,
    const short* __restrict__ wfm,
    float* __restrict__ sums,
    float* __restrict__ counts)
{
    __shared__ short X[TE][520];    // 33,280 B; pad 520 -> stride 260 dw (no 2^k alias)
    __shared__ int   sid[TE];
    __shared__ int   did[TE];
    __shared__ float dtS[TE];

    const int tid = threadIdx.x;
    const int e0  = blockIdx.x * TE;

    if (tid < TE) {
        int s = src[e0 + tid];
        int d = dst[e0 + tid];
        sid[tid] = s;
        did[tid] = d;
        dtS[tid] = timestamps[e0 + tid] - last_update[s];
        atomicAdd(&counts[s], 1.0f);
        atomicAdd(&counts[d], 1.0f);
    }
    __syncthreads();

    // Stage raw as bf16: 32 rows x 128 float4-chunks (k 484..511 zero-padded)
    for (int i = tid; i < TE * 128; i += 256) {
        int e = i >> 7;
        int c = (i & 127) * 4;
        float4 v;
        if (c < 128) {
            v = *reinterpret_cast<const float4*>(&memory[(size_t)sid[e] * 128 + c]);
        } else if (c < 256) {
            v = *reinterpret_cast<const float4*>(&memory[(size_t)did[e] * 128 + (c - 128)]);
        } else if (c < 384) {
            v = *reinterpret_cast<const float4*>(&edge_features[(size_t)(e0 + e) * 128 + (c - 256)]);
        } else if (c < 484) {
            float dt = dtS[e];
            int t = c - 384;
            v.x = __cosf(fmaf(dt, time_w[t + 0], time_b[t + 0]));
            v.y = __cosf(fmaf(dt, time_w[t + 1], time_b[t + 1]));
            v.z = __cosf(fmaf(dt, time_w[t + 2], time_b[t + 2]));
            v.w = __cosf(fmaf(dt, time_w[t + 3], time_b[t + 3]));
        } else {
            v.x = v.y = v.z = v.w = 0.0f;
        }
        short4 s4;
        s4.x = f2bf(v.x); s4.y = f2bf(v.y); s4.z = f2bf(v.z); s4.w = f2bf(v.w);
        *reinterpret_cast<short4*>(&X[e][c]) = s4;
    }
    __syncthreads();

    const int w    = tid >> 6;
    const int l    = tid & 63;
    const int lrow = l & 15;
    const int lkg  = l >> 4;
    const int et   = w & 1;    // edge tile (16 edges)
    const int nh   = w >> 1;   // output half (64 outputs)

    f32x4 acc[4];
#pragma unroll
    for (int n = 0; n < 4; n++) acc[n] = (f32x4){0.f, 0.f, 0.f, 0.f};

#pragma unroll 4
    for (int s = 0; s < 16; ++s) {
        bf16x8 A = *reinterpret_cast<const bf16x8*>(&X[et * 16 + lrow][s * 32 + lkg * 8]);
#pragma unroll
        for (int ntl = 0; ntl < 4; ++ntl) {
            int t = nh * 4 + ntl;
            bf16x8 B = *reinterpret_cast<const bf16x8*>(&wfm[(size_t)(((t * 16 + s) * 64) + l) * 8]);
            acc[ntl] = __builtin_amdgcn_mfma_f32_16x16x32_bf16(A, B, acc[ntl], 0, 0, 0);
        }
    }

    // Epilogue: bias + atomic scatter to both endpoints.
#pragma unroll
    for (int ntl = 0; ntl < 4; ++ntl) {
        int j = nh * 64 + ntl * 16 + lrow;
        float bias = msg_b[j];
#pragma unroll
        for (int r = 0; r < 4; ++r) {
            int el = et * 16 + lkg * 4 + r;
            float m = acc[ntl][r] + bias;
            atomicAdd(&sums[(size_t)sid[el] * 128 + j], m);
            atomicAdd(&sums[(size_t)did[el] * 128 + j], m);
        }
    }
}

// ---------------------------------------------------------------------------
// Kernel B: fused MFMA GEMM + GRU gates.  64 nodes/block, 256 threads.
// ---------------------------------------------------------------------------
#define NT 64

__global__ __launch_bounds__(256, 2) void tgn_gru_mfma(
    const float* __restrict__ memory,
    const float* __restrict__ last_update,
    const float* __restrict__ timestamps,
    const float* __restrict__ b_ih,
    const float* __restrict__ b_hh,
    const short* __restrict__ wfrag,
    float* __restrict__ out)
{
    __shared__ short X[NT][264];
    __shared__ float cntS[NT];

    const int tid = threadIdx.x;
    const int n0 = blockIdx.x * NT;
    const float* sums   = out;
    const float* counts = out + (size_t)N_NODES * 128;

    if (tid < NT) cntS[tid] = counts[n0 + tid];
    __syncthreads();

    for (int i = tid; i < NT * 64; i += 256) {
        int m = i >> 6;
        int c = (i & 63) * 4;
        float4 v;
        if (c < 128) {
            v = *reinterpret_cast<const float4*>(&sums[(size_t)(n0 + m) * 128 + c]);
            float inv = 1.0f / fmaxf(cntS[m], 1.0f);
            v.x *= inv; v.y *= inv; v.z *= inv; v.w *= inv;
        } else {
            v = *reinterpret_cast<const float4*>(&memory[(size_t)(n0 + m) * 128 + (c - 128)]);
        }
        X[m][c + 0] = f2bf(v.x);
        X[m][c + 1] = f2bf(v.y);
        X[m][c + 2] = f2bf(v.z);
        X[m][c + 3] = f2bf(v.w);
    }
    __syncthreads();

    const int w    = tid >> 6;
    const int l    = tid & 63;
    const int lrow = l & 15;
    const int lkg  = l >> 4;

    f32x4 acc[4][2][4];   // [quadrant][jt][mt]
#pragma unroll
    for (int q = 0; q < 4; q++)
#pragma unroll
        for (int jt = 0; jt < 2; jt++)
#pragma unroll
            for (int mt = 0; mt < 4; mt++)
                acc[q][jt][mt] = (f32x4){0.f, 0.f, 0.f, 0.f};

    for (int s = 0; s < 8; ++s) {
        bf16x8 A[4];
#pragma unroll
        for (int mt = 0; mt < 4; ++mt)
            A[mt] = *reinterpret_cast<const bf16x8*>(&X[mt * 16 + lrow][s * 32 + lkg * 8]);
        bf16x8 B[4][2];
#pragma unroll
        for (int q = 0; q < 4; ++q)
#pragma unroll
            for (int jt = 0; jt < 2; ++jt) {
                int t = q * 8 + w * 2 + jt;
                B[q][jt] = *reinterpret_cast<const bf16x8*>(&wfrag[(size_t)(((t * 8 + s) * 64) + l) * 8]);
            }
#pragma unroll
        for (int q = 0; q < 4; ++q)
#pragma unroll
            for (int jt = 0; jt < 2; ++jt)
#pragma unroll
                for (int mt = 0; mt < 4; ++mt)
                    acc[q][jt][mt] = __builtin_amdgcn_mfma_f32_16x16x32_bf16(
                        A[mt], B[q][jt], acc[q][jt][mt], 0, 0, 0);
    }

    const float ts0 = timestamps[0];

#pragma unroll
    for (int jt = 0; jt < 2; ++jt) {
        int j = w * 32 + jt * 16 + lrow;
        float br  = b_ih[j]       + b_hh[j];
        float bz  = b_ih[128 + j] + b_hh[128 + j];
        float bin = b_ih[256 + j];
        float bhn = b_hh[256 + j];
#pragma unroll
        for (int mt = 0; mt < 4; ++mt) {
#pragma unroll
            for (int r = 0; r < 4; ++r) {
                int mloc = mt * 16 + lkg * 4 + r;
                int node = n0 + mloc;
                float rg  = acc[0][jt][mt][r] + br;
                float zg  = acc[1][jt][mt][r] + bz;
                float ing = acc[2][jt][mt][r] + bin;
                float hng = acc[3][jt][mt][r] + bhn;
                float rr = 1.0f / (1.0f + __expf(-rg));
                float zz = 1.0f / (1.0f + __expf(-zg));
                float nn = tanhf(ing + rr * hng);
                float mv = memory[(size_t)node * 128 + j];
                float h  = (1.0f - zz) * nn + zz * mv;
                out[(size_t)node * 128 + j] = (cntS[mloc] > 0.0f) ? h : mv;
            }
        }
    }

    if (tid < NT) {
        int node = n0 + tid;
        out[(size_t)N_NODES * 128 + node] = (cntS[tid] > 0.0f) ? ts0 : last_update[node];
    }
}

// ---------------------------------------------------------------------------
extern "C" void kernel_launch(void* const* d_in, const int* in_sizes, int n_in,
                              void* d_out, int out_size, void* d_ws, size_t ws_size,
                              hipStream_t stream) {
    const float* memory        = (const float*)d_in[0];
    const float* last_update   = (const float*)d_in[1];
    const float* timestamps    = (const float*)d_in[2];
    const float* edge_features = (const float*)d_in[3];
    const float* msg_W         = (const float*)d_in[4];
    const float* msg_b         = (const float*)d_in[5];
    const float* gru_W_ih      = (const float*)d_in[6];
    const float* gru_W_hh      = (const float*)d_in[7];
    const float* gru_b_ih      = (const float*)d_in[8];
    const float* gru_b_hh      = (const float*)d_in[9];
    const float* time_w        = (const float*)d_in[10];
    const float* time_b        = (const float*)d_in[11];
    const int*   src           = (const int*)d_in[12];
    const int*   dst           = (const int*)d_in[13];

    float* out = (float*)d_out;
    short* wfrag_gru = (short*)d_ws;            // 131072 bf16 = 256 KB
    short* wfrag_msg = (short*)d_ws + 131072;   //  65536 bf16 = 128 KB

    hipMemsetAsync(d_out, 0, (size_t)out_size * sizeof(float), stream);

    float* sums   = out;
    float* counts = out + (size_t)N_NODES * 128;

    tgn_prep_wgru<<<512, 256, 0, stream>>>(gru_W_ih, gru_W_hh, wfrag_gru);
    tgn_prep_wmsg<<<256, 256, 0, stream>>>(msg_W, wfrag_msg);

    tgn_msg_mfma<<<E_EDGES / TE, 256, 0, stream>>>(
        memory, last_update, timestamps, edge_features, msg_b,
        time_w, time_b, src, dst, wfrag_msg, sums, counts);

    tgn_gru_mfma<<<N_NODES / NT, 256, 0, stream>>>(
        memory, last_update, timestamps, gru_b_ih, gru_b_hh, wfrag_gru, out);
}

// Round 4
// 346.344 us; speedup vs baseline: 14.6620x; 1.1927x over previous
//
#include <hip/hip_runtime.h>
#include <math.h>

#define N_NODES 200000
#define E_EDGES 100000
#define TIME_DIM 100
#define RAW_DIM 484   // 128 + 128 + 128 + 100

typedef short  bf16x8 __attribute__((ext_vector_type(8)));
typedef float  f32x4  __attribute__((ext_vector_type(4)));

__device__ __forceinline__ short f2bf(float f) {
    unsigned u = __builtin_bit_cast(unsigned, f);
    u = (u + 0x7FFFu + ((u >> 16) & 1u)) >> 16;   // RNE
    return (short)u;
}
__device__ __forceinline__ float bf2f(unsigned short u) {
    return __builtin_bit_cast(float, ((unsigned)u) << 16);
}
__device__ __forceinline__ float fsigmoid(float x) {
    return __builtin_amdgcn_rcpf(1.0f + __expf(-x));
}
__device__ __forceinline__ float ftanh(float x) {
    float t = __expf(2.0f * x);
    return 1.0f - 2.0f * __builtin_amdgcn_rcpf(t + 1.0f);
}
__device__ __forceinline__ void atomic_pk_add_bf16(short* addr, unsigned v) {
    asm volatile("global_atomic_pk_add_bf16 %0, %1, off" :: "v"(addr), "v"(v) : "memory");
}

// ---------------------------------------------------------------------------
// Prep 1: pack msg_W [128][484] -> bf16 B-fragment order, K padded to 512.
// ---------------------------------------------------------------------------
__global__ __launch_bounds__(256) void tgn_prep_wmsg(
    const float* __restrict__ msgW, short* __restrict__ wf)
{
    int idx = blockIdx.x * 256 + threadIdx.x;   // 0 .. 65535
    int j = idx & 7;
    int l = (idx >> 3) & 63;
    int s = (idx >> 9) & 15;
    int t = idx >> 13;
    int n = t * 16 + (l & 15);
    int k = s * 32 + (l >> 4) * 8 + j;
    float v = (k < RAW_DIM) ? msgW[(size_t)n * RAW_DIM + k] : 0.0f;
    wf[idx] = f2bf(v);
}

// ---------------------------------------------------------------------------
// Prep 2: pack combined GRU weight matrix W_big[512][256] into B-frag order.
// ---------------------------------------------------------------------------
__global__ __launch_bounds__(256) void tgn_prep_wgru(
    const float* __restrict__ Wih, const float* __restrict__ Whh,
    short* __restrict__ wf)
{
    int idx = blockIdx.x * 256 + threadIdx.x;   // 0 .. 131071
    int j = idx & 7;
    int l = (idx >> 3) & 63;
    int s = (idx >> 9) & 7;
    int t = idx >> 12;
    int n = t * 16 + (l & 15);
    int k = s * 32 + (l >> 4) * 8 + j;
    int half = k >> 7;
    int kk = k & 127;
    float v;
    if (n < 256) {
        v = half ? Whh[(size_t)n * 128 + kk] : Wih[(size_t)n * 128 + kk];
    } else if (n < 384) {
        v = half ? 0.0f : Wih[(size_t)n * 128 + kk];
    } else {
        v = half ? Whh[(size_t)(n - 128) * 128 + kk] : 0.0f;
    }
    wf[idx] = f2bf(v);
}

// ---------------------------------------------------------------------------
// Kernel A: MFMA message MLP + scatter-add.
// PK=true: packed bf16 atomics into sums_bf (d_ws). PK=false: f32 atomicAdd.
// ---------------------------------------------------------------------------
#define TE 32

template<bool PK>
__global__ __launch_bounds__(256, 2) void tgn_msg_mfma(
    const float* __restrict__ memory,
    const float* __restrict__ last_update,
    const float* __restrict__ timestamps,
    const float* __restrict__ edge_features,
    const float* __restrict__ msg_b,
    const float* __restrict__ time_w,
    const float* __restrict__ time_b,
    const int*   __restrict__ src,
    const int*   __restrict__ dst,
    const short* __restrict__ wfm,
    short* __restrict__ sums_bf,
    float* __restrict__ sums_f,
    float* __restrict__ counts)
{
    __shared__ short X[TE][520];
    __shared__ int   sid[TE];
    __shared__ int   did[TE];
    __shared__ float dtS[TE];

    const int tid = threadIdx.x;
    const int e0  = blockIdx.x * TE;

    if (tid < TE) {
        int s = src[e0 + tid];
        int d = dst[e0 + tid];
        sid[tid] = s;
        did[tid] = d;
        dtS[tid] = timestamps[e0 + tid] - last_update[s];
        atomicAdd(&counts[s], 1.0f);
        atomicAdd(&counts[d], 1.0f);
    }
    __syncthreads();

    for (int i = tid; i < TE * 128; i += 256) {
        int e = i >> 7;
        int c = (i & 127) * 4;
        float4 v;
        if (c < 128) {
            v = *reinterpret_cast<const float4*>(&memory[(size_t)sid[e] * 128 + c]);
        } else if (c < 256) {
            v = *reinterpret_cast<const float4*>(&memory[(size_t)did[e] * 128 + (c - 128)]);
        } else if (c < 384) {
            v = *reinterpret_cast<const float4*>(&edge_features[(size_t)(e0 + e) * 128 + (c - 256)]);
        } else if (c < 484) {
            float dt = dtS[e];
            int t = c - 384;
            v.x = __cosf(fmaf(dt, time_w[t + 0], time_b[t + 0]));
            v.y = __cosf(fmaf(dt, time_w[t + 1], time_b[t + 1]));
            v.z = __cosf(fmaf(dt, time_w[t + 2], time_b[t + 2]));
            v.w = __cosf(fmaf(dt, time_w[t + 3], time_b[t + 3]));
        } else {
            v.x = v.y = v.z = v.w = 0.0f;
        }
        short4 s4;
        s4.x = f2bf(v.x); s4.y = f2bf(v.y); s4.z = f2bf(v.z); s4.w = f2bf(v.w);
        *reinterpret_cast<short4*>(&X[e][c]) = s4;
    }
    __syncthreads();

    const int w    = tid >> 6;
    const int l    = tid & 63;
    const int lrow = l & 15;
    const int lkg  = l >> 4;
    const int et   = w & 1;    // edge tile (16 edges)
    const int nh   = w >> 1;   // output half (64 outputs)

    f32x4 acc[4];
#pragma unroll
    for (int n = 0; n < 4; n++) acc[n] = (f32x4){0.f, 0.f, 0.f, 0.f};

#pragma unroll 4
    for (int s = 0; s < 16; ++s) {
        bf16x8 A = *reinterpret_cast<const bf16x8*>(&X[et * 16 + lrow][s * 32 + lkg * 8]);
#pragma unroll
        for (int ntl = 0; ntl < 4; ++ntl) {
            int t = nh * 4 + ntl;
            bf16x8 B = *reinterpret_cast<const bf16x8*>(&wfm[(size_t)(((t * 16 + s) * 64) + l) * 8]);
            acc[ntl] = __builtin_amdgcn_mfma_f32_16x16x32_bf16(A, B, acc[ntl], 0, 0, 0);
        }
    }

    const bool even = (l & 1) == 0;
#pragma unroll
    for (int ntl = 0; ntl < 4; ++ntl) {
        int j = nh * 64 + ntl * 16 + lrow;
        float bias = msg_b[j];
#pragma unroll
        for (int r = 0; r < 4; ++r) {
            int el = et * 16 + lkg * 4 + r;
            float m = acc[ntl][r] + bias;
            if (PK) {
                float mo = __shfl_xor(m, 1);
                unsigned mb  = (unsigned short)f2bf(m);
                unsigned mob = (unsigned short)f2bf(mo);
                unsigned pk = even ? (mb | (mob << 16)) : (mob | (mb << 16));
                int node = even ? sid[el] : did[el];
                int jj = j & ~1;
                atomic_pk_add_bf16(&sums_bf[(size_t)node * 128 + jj], pk);
            } else {
                atomicAdd(&sums_f[(size_t)sid[el] * 128 + j], m);
                atomicAdd(&sums_f[(size_t)did[el] * 128 + j], m);
            }
        }
    }
}

// ---------------------------------------------------------------------------
// Kernel B: fused MFMA GEMM + GRU gates.  32 nodes/block, 256 threads.
// Wave w owns j-slice [w*32, w*32+32), all 4 gate quadrants, 2 node tiles.
// acc = 16 tiles = 64 AGPR -> 3 waves/SIMD.
// ---------------------------------------------------------------------------
#define GNT 32

template<bool PK>
__global__ __launch_bounds__(256, 3) void tgn_gru_mfma(
    const float* __restrict__ memory,
    const float* __restrict__ last_update,
    const float* __restrict__ timestamps,
    const float* __restrict__ b_ih,
    const float* __restrict__ b_hh,
    const short* __restrict__ wfrag,
    const short* __restrict__ sums_bf,
    const float* __restrict__ sums_f,
    const float* __restrict__ counts,
    float* __restrict__ out)
{
    __shared__ short X[GNT][264];
    __shared__ float cntS[GNT];

    const int tid = threadIdx.x;
    const int n0 = blockIdx.x * GNT;

    if (tid < GNT) cntS[tid] = counts[n0 + tid];
    __syncthreads();

    // Stage X = [agg | mem] as bf16: 32 nodes x 32 4-elem granules each half.
    for (int i = tid; i < GNT * 32; i += 256) {
        int m = i >> 5;
        int c = (i & 31) * 4;
        float inv = 1.0f / fmaxf(cntS[m], 1.0f);
        short4 a4;
        if (PK) {
            ushort4 u = *reinterpret_cast<const ushort4*>(&sums_bf[(size_t)(n0 + m) * 128 + c]);
            a4.x = f2bf(bf2f(u.x) * inv);
            a4.y = f2bf(bf2f(u.y) * inv);
            a4.z = f2bf(bf2f(u.z) * inv);
            a4.w = f2bf(bf2f(u.w) * inv);
        } else {
            float4 v = *reinterpret_cast<const float4*>(&sums_f[(size_t)(n0 + m) * 128 + c]);
            a4.x = f2bf(v.x * inv);
            a4.y = f2bf(v.y * inv);
            a4.z = f2bf(v.z * inv);
            a4.w = f2bf(v.w * inv);
        }
        *reinterpret_cast<short4*>(&X[m][c]) = a4;
        float4 mv = *reinterpret_cast<const float4*>(&memory[(size_t)(n0 + m) * 128 + c]);
        short4 m4;
        m4.x = f2bf(mv.x); m4.y = f2bf(mv.y); m4.z = f2bf(mv.z); m4.w = f2bf(mv.w);
        *reinterpret_cast<short4*>(&X[m][128 + c]) = m4;
    }
    __syncthreads();

    const int w    = tid >> 6;
    const int l    = tid & 63;
    const int lrow = l & 15;
    const int lkg  = l >> 4;

    f32x4 acc[4][2][2];   // [quadrant][jt][mt]
#pragma unroll
    for (int q = 0; q < 4; q++)
#pragma unroll
        for (int jt = 0; jt < 2; jt++)
#pragma unroll
            for (int mt = 0; mt < 2; mt++)
                acc[q][jt][mt] = (f32x4){0.f, 0.f, 0.f, 0.f};

    for (int s = 0; s < 8; ++s) {
        bf16x8 A[2];
#pragma unroll
        for (int mt = 0; mt < 2; ++mt)
            A[mt] = *reinterpret_cast<const bf16x8*>(&X[mt * 16 + lrow][s * 32 + lkg * 8]);
#pragma unroll
        for (int q = 0; q < 4; ++q)
#pragma unroll
            for (int jt = 0; jt < 2; ++jt) {
                int t = q * 8 + w * 2 + jt;
                bf16x8 B = *reinterpret_cast<const bf16x8*>(&wfrag[(size_t)(((t * 8 + s) * 64) + l) * 8]);
#pragma unroll
                for (int mt = 0; mt < 2; ++mt)
                    acc[q][jt][mt] = __builtin_amdgcn_mfma_f32_16x16x32_bf16(
                        A[mt], B, acc[q][jt][mt], 0, 0, 0);
            }
    }

    const float ts0 = timestamps[0];

#pragma unroll
    for (int jt = 0; jt < 2; ++jt) {
        int j = w * 32 + jt * 16 + lrow;
        float br  = b_ih[j]       + b_hh[j];
        float bz  = b_ih[128 + j] + b_hh[128 + j];
        float bin = b_ih[256 + j];
        float bhn = b_hh[256 + j];
#pragma unroll
        for (int mt = 0; mt < 2; ++mt) {
#pragma unroll
            for (int r = 0; r < 4; ++r) {
                int mloc = mt * 16 + lkg * 4 + r;
                int node = n0 + mloc;
                float rg  = acc[0][jt][mt][r] + br;
                float zg  = acc[1][jt][mt][r] + bz;
                float ing = acc[2][jt][mt][r] + bin;
                float hng = acc[3][jt][mt][r] + bhn;
                float rr = fsigmoid(rg);
                float zz = fsigmoid(zg);
                float nn = ftanh(ing + rr * hng);
                float mv = memory[(size_t)node * 128 + j];
                float h  = (1.0f - zz) * nn + zz * mv;
                out[(size_t)node * 128 + j] = (cntS[mloc] > 0.0f) ? h : mv;
            }
        }
    }

    if (tid < GNT) {
        int node = n0 + tid;
        out[(size_t)N_NODES * 128 + node] = (cntS[tid] > 0.0f) ? ts0 : last_update[node];
    }
}

// ---------------------------------------------------------------------------
extern "C" void kernel_launch(void* const* d_in, const int* in_sizes, int n_in,
                              void* d_out, int out_size, void* d_ws, size_t ws_size,
                              hipStream_t stream) {
    const float* memory        = (const float*)d_in[0];
    const float* last_update   = (const float*)d_in[1];
    const float* timestamps    = (const float*)d_in[2];
    const float* edge_features = (const float*)d_in[3];
    const float* msg_W         = (const float*)d_in[4];
    const float* msg_b         = (const float*)d_in[5];
    const float* gru_W_ih      = (const float*)d_in[6];
    const float* gru_W_hh      = (const float*)d_in[7];
    const float* gru_b_ih      = (const float*)d_in[8];
    const float* gru_b_hh      = (const float*)d_in[9];
    const float* time_w        = (const float*)d_in[10];
    const float* time_b        = (const float*)d_in[11];
    const int*   src           = (const int*)d_in[12];
    const int*   dst           = (const int*)d_in[13];

    float* out = (float*)d_out;
    short* wfrag_gru = (short*)d_ws;            // 131072 bf16 = 256 KB
    short* wfrag_msg = (short*)d_ws + 131072;   //  65536 bf16 = 128 KB

    // PK layout in ws: sums_bf (N*128 bf16 = 51.2 MB) + counts (N f32 = 0.8 MB)
    short* sums_bf   = (short*)d_ws + 196608;
    float* counts_ws = (float*)((char*)d_ws + 393216 + (size_t)N_NODES * 128 * 2);
    const size_t ws_needed = 393216 + (size_t)N_NODES * 128 * 2 + (size_t)N_NODES * 4;

    tgn_prep_wgru<<<512, 256, 0, stream>>>(gru_W_ih, gru_W_hh, wfrag_gru);
    tgn_prep_wmsg<<<256, 256, 0, stream>>>(msg_W, wfrag_msg);

    if (ws_size >= ws_needed) {
        // zero sums_bf + counts (contiguous)
        hipMemsetAsync(sums_bf, 0, (size_t)N_NODES * 128 * 2 + (size_t)N_NODES * 4, stream);

        tgn_msg_mfma<true><<<E_EDGES / TE, 256, 0, stream>>>(
            memory, last_update, timestamps, edge_features, msg_b,
            time_w, time_b, src, dst, wfrag_msg, sums_bf, nullptr, counts_ws);

        tgn_gru_mfma<true><<<N_NODES / GNT, 256, 0, stream>>>(
            memory, last_update, timestamps, gru_b_ih, gru_b_hh, wfrag_gru,
            sums_bf, nullptr, counts_ws, out);
    } else {
        // Fallback: f32 sums/counts live inside d_out.
        hipMemsetAsync(d_out, 0, (size_t)out_size * sizeof(float), stream);
        float* sums_f = out;
        float* counts = out + (size_t)N_NODES * 128;

        tgn_msg_mfma<false><<<E_EDGES / TE, 256, 0, stream>>>(
            memory, last_update, timestamps, edge_features, msg_b,
            time_w, time_b, src, dst, wfrag_msg, nullptr, sums_f, counts);

        tgn_gru_mfma<false><<<N_NODES / GNT, 256, 0, stream>>>(
            memory, last_update, timestamps, gru_b_ih, gru_b_hh, wfrag_gru,
            nullptr, sums_f, counts, out);
    }
}